// Round 1
// baseline (191.076 us; speedup 1.0000x reference)
//
#include <hip/hip_runtime.h>
#include <hip/hip_bf16.h>
#include <math.h>

typedef __attribute__((ext_vector_type(4))) float f32x4;
typedef __attribute__((ext_vector_type(8))) short s16x8;
typedef __attribute__((ext_vector_type(4))) short s16x4;

#define NB 8
#define NT 2048
#define NC 1024
#define NH 128
// log2(e)/sqrt(C) folded into Q at projection time (exp2-domain softmax)
#define QSCALE 0.04508422002778f

__device__ __forceinline__ short f2bf(float f) {
  union { float f; unsigned u; } v; v.f = f;
  unsigned r = v.u + 0x7fffu + ((v.u >> 16) & 1u);
  return (short)(r >> 16);
}

// ---------------- kernel 0: W [C][H] fp32 -> Wt [3][H][C] bf16 (transposed) --
__global__ void wt_kernel(const float* __restrict__ Wq, const float* __restrict__ Wk,
                          const float* __restrict__ Wv, short* __restrict__ Wt) {
  int idx = blockIdx.x * 256 + threadIdx.x;  // 3*128*1024
  if (idx >= 3 * 128 * 1024) return;
  int m = idx >> 17;
  int n = (idx >> 10) & 127;
  int k = idx & 1023;
  const float* W = (m == 0) ? Wq : ((m == 1) ? Wk : Wv);
  Wt[idx] = f2bf(W[k * 128 + n]);
}

// ---------------- kernel 1: QKV projection ---------------------------------
// grid (128, 3): x-tile of 128 rows, y = which projection (0=Q,1=K,2=V)
// out: Q,K row-major bf16 [BT][H]; V transposed: Vt[b][d][t] bf16
#define PK_PAD 72   // 64 + 8 pad (bank-conflict-free, 16B-multiple stride)
#define PT_PAD 136  // 128 + 8 pad

__global__ __launch_bounds__(256)
void proj_kernel(const float* __restrict__ x, const short* __restrict__ Wt,
                 const float* __restrict__ bq, const float* __restrict__ bk,
                 const float* __restrict__ bv,
                 short* __restrict__ Qb, short* __restrict__ Kb, short* __restrict__ Vtb) {
  __shared__ __align__(16) char smem[2 * 128 * PK_PAD * 2];  // 36864 B
  short* Ax = (short*)smem;                       // [128][PK_PAD]
  short* Bw = (short*)(smem + 128 * PK_PAD * 2);  // [128][PK_PAD]
  short* Tr = (short*)smem;                       // [128][PT_PAD] (epilogue reuse, 34816 B)

  const int tid = threadIdx.x;
  const int m0 = blockIdx.x * 128;
  const int proj = blockIdx.y;
  const int w = tid >> 6, lane = tid & 63;
  const int lr = lane & 15, lg = lane >> 4;

  f32x4 acc[2][8];
#pragma unroll
  for (int i = 0; i < 2; i++)
#pragma unroll
    for (int j = 0; j < 8; j++) acc[i][j] = {0.f, 0.f, 0.f, 0.f};

  const short* Wtp = Wt + proj * (128 * 1024);

  for (int k0 = 0; k0 < NC; k0 += 64) {
    // stage A: x tile 128 rows x 64 k, fp32 -> bf16
#pragma unroll
    for (int i = 0; i < 4; i++) {
      int idx = tid + 256 * i;       // 0..1023 chunks of 8
      int row = idx >> 3, c8 = idx & 7;
      const float* src = x + (size_t)(m0 + row) * NC + k0 + c8 * 8;
      float4 a = *(const float4*)src;
      float4 b = *(const float4*)(src + 4);
      s16x8 v;
      v[0] = f2bf(a.x); v[1] = f2bf(a.y); v[2] = f2bf(a.z); v[3] = f2bf(a.w);
      v[4] = f2bf(b.x); v[5] = f2bf(b.y); v[6] = f2bf(b.z); v[7] = f2bf(b.w);
      *(s16x8*)(Ax + row * PK_PAD + c8 * 8) = v;
    }
    // stage B: Wt rows (already transposed, bf16) 128 n x 64 k
#pragma unroll
    for (int i = 0; i < 4; i++) {
      int idx = tid + 256 * i;
      int n = idx >> 3, c8 = idx & 7;
      s16x8 v = *(const s16x8*)(Wtp + n * 1024 + k0 + c8 * 8);
      *(s16x8*)(Bw + n * PK_PAD + c8 * 8) = v;
    }
    __syncthreads();
#pragma unroll
    for (int kc = 0; kc < 2; kc++) {
      s16x8 af[2];
#pragma unroll
      for (int mi = 0; mi < 2; mi++) {
        int row = w * 32 + mi * 16 + lr;
        af[mi] = *(const s16x8*)(Ax + row * PK_PAD + kc * 32 + lg * 8);
      }
#pragma unroll
      for (int ni = 0; ni < 8; ni++) {
        s16x8 bf = *(const s16x8*)(Bw + (ni * 16 + lr) * PK_PAD + kc * 32 + lg * 8);
        acc[0][ni] = __builtin_amdgcn_mfma_f32_16x16x32_bf16(af[0], bf, acc[0][ni], 0, 0, 0);
        acc[1][ni] = __builtin_amdgcn_mfma_f32_16x16x32_bf16(af[1], bf, acc[1][ni], 0, 0, 0);
      }
    }
    __syncthreads();
  }

  const float* bias = (proj == 0) ? bq : ((proj == 1) ? bk : bv);
  const float scl = (proj == 0) ? QSCALE : 1.0f;

  if (proj < 2) {
    // Tr[t][d], then coalesced row-major write
#pragma unroll
    for (int mi = 0; mi < 2; mi++)
#pragma unroll
      for (int ni = 0; ni < 8; ni++) {
        float bn = bias[ni * 16 + lr];
#pragma unroll
        for (int r = 0; r < 4; r++) {
          int t = w * 32 + mi * 16 + lg * 4 + r;
          Tr[t * PT_PAD + ni * 16 + lr] = f2bf((acc[mi][ni][r] + bn) * scl);
        }
      }
    __syncthreads();
    short* dst = (proj == 0) ? Qb : Kb;
#pragma unroll
    for (int i = 0; i < 8; i++) {
      int c = tid + 256 * i;  // 0..2047
      int t = c >> 4, c8 = c & 15;
      s16x8 v = *(const s16x8*)(Tr + t * PT_PAD + c8 * 8);
      *(s16x8*)(dst + (size_t)(m0 + t) * NH + c8 * 8) = v;
    }
  } else {
    // Tr as T2[d][t]: transpose in LDS, write Vt[b][d][t]
#pragma unroll
    for (int mi = 0; mi < 2; mi++)
#pragma unroll
      for (int ni = 0; ni < 8; ni++) {
        float bn = bias[ni * 16 + lr];
        int d = ni * 16 + lr;
        int t = w * 32 + mi * 16 + lg * 4;
        s16x4 v;
        v[0] = f2bf(acc[mi][ni][0] + bn);
        v[1] = f2bf(acc[mi][ni][1] + bn);
        v[2] = f2bf(acc[mi][ni][2] + bn);
        v[3] = f2bf(acc[mi][ni][3] + bn);
        *(s16x4*)(Tr + d * PT_PAD + t) = v;
      }
    __syncthreads();
    int b = m0 >> 11;
    int tb = m0 & 2047;
#pragma unroll
    for (int i = 0; i < 8; i++) {
      int c = tid + 256 * i;
      int d = c >> 4, c8 = c & 15;
      s16x8 v = *(const s16x8*)(Tr + d * PT_PAD + c8 * 8);
      *(s16x8*)(Vtb + (size_t)b * (NH * NT) + (size_t)d * NT + tb + c8 * 8) = v;
    }
  }
}

// ---------------- kernel 2: causal flash attention -------------------------
// 512 blocks (8 batches x 64 q-tiles of 32), 2 waves/block (16 q-rows each).
// Swapped QK^T (S^T = K*Q^T) => lane owns q = lane&15, k = km*16+4*lg+r.
// PV uses permuted-k-slot mfma: slot (lg,j) -> k = 32ks + 16*(j>>2) + 4*lg + (j&3),
// matching the S^T layout exactly => P feeds MFMA with no cross-lane traffic.
#define KPAD 136  // 128 + 8
#define VPAD 72   // 64 + 8

__global__ __launch_bounds__(128)
void attn_kernel(const short* __restrict__ Qb, const short* __restrict__ Kb,
                 const short* __restrict__ Vtb, float* __restrict__ out) {
  __shared__ __align__(16) short Kl[64 * KPAD];   // 17408 B
  __shared__ __align__(16) short Vl[128 * VPAD];  // 18432 B

  const int tid = threadIdx.x;
  const int w = tid >> 6, lane = tid & 63;
  const int lr = lane & 15, lg = lane >> 4;

  const int bid = blockIdx.x;
  const int batch = bid >> 6;
  const int qtile = 63 - (bid & 63);  // heavy tiles dispatched first
  const int q0 = qtile * 32;

  const int qrow = q0 + w * 16 + lr;  // within batch
  const short* Qrow = Qb + (size_t)(batch * NT + qrow) * NH;
  s16x8 qf[4];
#pragma unroll
  for (int dc = 0; dc < 4; dc++) qf[dc] = *(const s16x8*)(Qrow + dc * 32 + lg * 8);

  f32x4 acc[8];
#pragma unroll
  for (int i = 0; i < 8; i++) acc[i] = {0.f, 0.f, 0.f, 0.f};
  float m_run = -3.0e38f, l_run = 0.f;

  const int ntiles = (q0 + 95) >> 6;  // ceil((q0+32)/64)
  const short* Kbase = Kb + (size_t)batch * NT * NH;
  const short* Vbase = Vtb + (size_t)batch * NH * NT;

  for (int it = 0; it < ntiles; it++) {
    const int kv0 = it * 64;
    // stage K tile [64][128]
#pragma unroll
    for (int i = 0; i < 8; i++) {
      int idx = tid + 128 * i;
      int row = idx >> 4, c8 = idx & 15;
      s16x8 v = *(const s16x8*)(Kbase + (size_t)(kv0 + row) * NH + c8 * 8);
      *(s16x8*)(Kl + row * KPAD + c8 * 8) = v;
    }
    // stage Vt tile [128 d][64 t]
#pragma unroll
    for (int i = 0; i < 8; i++) {
      int idx = tid + 128 * i;
      int d = idx >> 3, c8 = idx & 7;
      s16x8 v = *(const s16x8*)(Vbase + (size_t)d * NT + kv0 + c8 * 8);
      *(s16x8*)(Vl + d * VPAD + c8 * 8) = v;
    }
    __syncthreads();

    // S^T = K * Q^T
    f32x4 st[4];
#pragma unroll
    for (int km = 0; km < 4; km++) st[km] = {0.f, 0.f, 0.f, 0.f};
#pragma unroll
    for (int dc = 0; dc < 4; dc++)
#pragma unroll
      for (int km = 0; km < 4; km++) {
        s16x8 kf = *(const s16x8*)(Kl + (km * 16 + lr) * KPAD + dc * 32 + lg * 8);
        st[km] = __builtin_amdgcn_mfma_f32_16x16x32_bf16(kf, qf[dc], st[km], 0, 0, 0);
      }

    if (kv0 + 63 > q0) {  // diagonal tile: causal mask
#pragma unroll
      for (int km = 0; km < 4; km++)
#pragma unroll
        for (int r = 0; r < 4; r++) {
          int kg = kv0 + km * 16 + lg * 4 + r;
          if (kg > qrow) st[km][r] = -3.0e38f;
        }
    }

    // online softmax (exp2-domain; q-row reduce over lanes {l, l^16, l^32, l^48})
    float tm = -3.0e38f;
#pragma unroll
    for (int km = 0; km < 4; km++)
#pragma unroll
      for (int r = 0; r < 4; r++) tm = fmaxf(tm, st[km][r]);
    tm = fmaxf(tm, __shfl_xor(tm, 16, 64));
    tm = fmaxf(tm, __shfl_xor(tm, 32, 64));
    float m_new = fmaxf(m_run, tm);
    float corr = exp2f(m_run - m_new);

    float psum = 0.f;
    s16x8 pf[2];
#pragma unroll
    for (int km = 0; km < 4; km++)
#pragma unroll
      for (int r = 0; r < 4; r++) {
        float p = exp2f(st[km][r] - m_new);
        psum += p;
        pf[km >> 1][(km & 1) * 4 + r] = f2bf(p);
      }
    psum += __shfl_xor(psum, 16, 64);
    psum += __shfl_xor(psum, 32, 64);
    l_run = l_run * corr + psum;
    m_run = m_new;
#pragma unroll
    for (int i = 0; i < 8; i++) acc[i] *= corr;

    // O^T += Vt * P^T  (permuted k slots, see header comment)
#pragma unroll
    for (int ks = 0; ks < 2; ks++)
#pragma unroll
      for (int dm = 0; dm < 8; dm++) {
        const short* vp = Vl + (dm * 16 + lr) * VPAD + ks * 32 + lg * 4;
        s16x4 v0 = *(const s16x4*)vp;         // k = 32ks + 4lg + 0..3
        s16x4 v1 = *(const s16x4*)(vp + 16);  // k = 32ks + 16 + 4lg + 0..3
        s16x8 vf = __builtin_shufflevector(v0, v1, 0, 1, 2, 3, 4, 5, 6, 7);
        acc[dm] = __builtin_amdgcn_mfma_f32_16x16x32_bf16(vf, pf[ks], acc[dm], 0, 0, 0);
      }
    __syncthreads();
  }

  const float inv = 1.f / l_run;
  float* orow = out + (size_t)(batch * NT + qrow) * NH;
#pragma unroll
  for (int dm = 0; dm < 8; dm++) {
    float4 o;
    o.x = acc[dm][0] * inv;
    o.y = acc[dm][1] * inv;
    o.z = acc[dm][2] * inv;
    o.w = acc[dm][3] * inv;
    *(float4*)(orow + dm * 16 + lg * 4) = o;
  }
}

// ---------------- launch ----------------------------------------------------
extern "C" void kernel_launch(void* const* d_in, const int* in_sizes, int n_in,
                              void* d_out, int out_size, void* d_ws, size_t ws_size,
                              hipStream_t stream) {
  const float* x = (const float*)d_in[0];
  const float* Wq = (const float*)d_in[1];
  const float* bq = (const float*)d_in[2];
  const float* Wk = (const float*)d_in[3];
  const float* bk = (const float*)d_in[4];
  const float* Wv = (const float*)d_in[5];
  const float* bv = (const float*)d_in[6];
  float* out = (float*)d_out;

  char* ws = (char*)d_ws;
  short* Wt = (short*)ws;                              // 786432 B
  short* Qb = (short*)(ws + 786432);                   // 4 MiB
  short* Kb = (short*)(ws + 786432 + 4194304);         // 4 MiB
  short* Vtb = (short*)(ws + 786432 + 2 * 4194304);    // 4 MiB

  wt_kernel<<<dim3(1536), dim3(256), 0, stream>>>(Wq, Wk, Wv, Wt);
  proj_kernel<<<dim3(128, 3), dim3(256), 0, stream>>>(x, Wt, bq, bk, bv, Qb, Kb, Vtb);
  attn_kernel<<<dim3(512), dim3(128), 0, stream>>>(Qb, Kb, Vtb, out);
}